// Round 1
// baseline (1379.042 us; speedup 1.0000x reference)
//
#include <hip/hip_runtime.h>
#include <math.h>

#define B_ 4
#define L_ 5
#define P_ 1024
#define C_ 256
#define TOK (B_ * L_ * P_)   // 20480

// ---- workspace float offsets ----
// transposed feats (B,H,W,C):
#define FT0_OFF 0u
#define FT1_OFF 4194304u
#define FT2_OFF 6291456u
#define FT3_OFF 7340032u
#define FT4_OFF 7864320u
#define FT_TOTAL 8126464u
#define WTS_OFF  FT_TOTAL                 // TOK*32
#define POS_OFF  (FT_TOTAL + 655360u)     // TOK*64

// block-wide sum over 256 threads; `red` is a 256-float LDS buffer
__device__ __forceinline__ float block_sum256(float v, float* red, int c) {
  red[c] = v; __syncthreads();
  for (int s = 128; s > 0; s >>= 1) {
    if (c < s) red[c] += red[c + s];
    __syncthreads();
  }
  float r = red[0];
  __syncthreads();
  return r;
}

// (B,C,HW) -> (B,HW,C) tiled transpose. grid: (HW/64, C/32, B), block 256.
__global__ void transpose_feat(const float* __restrict__ src, float* __restrict__ dst,
                               int C, int HW) {
  __shared__ float tile[32][65];
  int b = blockIdx.z;
  int hw0 = blockIdx.x * 64;
  int c0 = blockIdx.y * 32;
  const float* s = src + (size_t)b * C * HW;
  float* d = dst + (size_t)b * HW * C;
  int tw = threadIdx.x & 63;          // 0..63
  int tc = threadIdx.x >> 6;          // 0..3
  for (int cc = tc; cc < 32; cc += 4)
    tile[cc][tw] = s[(size_t)(c0 + cc) * HW + hw0 + tw];
  __syncthreads();
  int tcl = threadIdx.x & 31;         // 0..31
  int thw = threadIdx.x >> 5;         // 0..7
  for (int ww = thw; ww < 64; ww += 8)
    d[(size_t)(hw0 + ww) * C + c0 + tcl] = tile[tcl][ww];
}

// out[:,0,:,:] = x[:,0,:,:]
__global__ void copy_x0(const float* __restrict__ x, float* __restrict__ out) {
  int i = blockIdx.x * 256 + threadIdx.x;          // B*P*C total
  int b = i / (P_ * C_);
  int r = i - b * (P_ * C_);
  size_t off = (size_t)b * 6 * P_ * C_ + r;
  out[off] = x[off];
}

// LN1 + attention-weight scores (softmax over NS=4) + sampling offsets (tanh)+ref
// grid: TOK blocks x 256 threads
__global__ void ln1_awso(const float* __restrict__ x, const float* __restrict__ ref,
                         const float* __restrict__ g, const float* __restrict__ bt,
                         const float* __restrict__ awW, const float* __restrict__ awb,
                         const float* __restrict__ soW, const float* __restrict__ sob,
                         float* __restrict__ wts, float* __restrict__ poss) {
  __shared__ float h[C_];
  __shared__ float red[C_];
  __shared__ float sc[96];
  int t = blockIdx.x;
  int b = t / (L_ * P_);
  int r = t - b * (L_ * P_);
  int l = r / P_;
  int p = r - l * P_;
  int c = threadIdx.x;

  size_t xq_off = (((size_t)b * 6 + (l + 1)) * P_ + p) * C_;
  size_t x0_off = (((size_t)b * 6) * P_ + p) * C_;
  float v = x[xq_off + c] + x[x0_off + c];

  float mean = block_sum256(v, red, c) * (1.0f / C_);
  float dv = v - mean;
  float var = block_sum256(dv * dv, red, c) * (1.0f / C_);
  h[c] = dv * rsqrtf(var + 1e-5f) * g[c] + bt[c];
  __syncthreads();

  if (c < 32) {
    float acc = awb[c];
    for (int i = 0; i < C_; i++) acc += h[i] * awW[i * 32 + c];
    sc[c] = acc;
  } else if (c < 96) {
    int j = c - 32;
    float acc = sob[j];
    for (int i = 0; i < C_; i++) acc += h[i] * soW[i * 64 + j];
    sc[c] = acc;
  }
  __syncthreads();

  if (c < 32) {
    int hh = c >> 2;
    float m = sc[hh * 4];
    for (int k = 1; k < 4; k++) m = fmaxf(m, sc[hh * 4 + k]);
    float den = 0.f;
    for (int k = 0; k < 4; k++) den += expf(sc[hh * 4 + k] - m);
    wts[(size_t)t * 32 + c] = expf(sc[c] - m) / den;
  } else if (c < 96) {
    int j = c - 32;
    int coord = j & 1;
    float pv = tanhf(sc[c]) + ref[((size_t)b * P_ + p) * 2 + coord];
    poss[(size_t)t * 64 + j] = pv;
  }
}

// bilinear sample (border clamp) + weighted combine over NS + per-level projection
// + residual.  Writes xq2 into d_out[:,1+l].  grid: TOK x 256 threads.
__global__ void sample_proj(const float* __restrict__ x, const float* __restrict__ ftt,
                            const float* __restrict__ wts, const float* __restrict__ poss,
                            const float* __restrict__ e0W, const float* __restrict__ e0b,
                            const float* __restrict__ e1W, const float* __restrict__ e1b,
                            const float* __restrict__ e2W, const float* __restrict__ e2b,
                            const float* __restrict__ e3W, const float* __restrict__ e3b,
                            const float* __restrict__ e4W, const float* __restrict__ e4b,
                            float* __restrict__ out) {
  __shared__ float coef[128];
  __shared__ int   hwid[128];
  __shared__ float vbuf[8 * 512];   // 16 KB max (level 3: C=512)
  int t = blockIdx.x;
  int b = t / (L_ * P_);
  int r = t - b * (L_ * P_);
  int l = r / P_;
  int p = r - l * P_;
  int tid = threadIdx.x;

  int Hl, Cl; size_t fo; const float* eW; const float* eb;
  if (l == 0)      { Hl = 128; Cl = 64;  fo = FT0_OFF; eW = e0W; eb = e0b; }
  else if (l == 1) { Hl = 64;  Cl = 128; fo = FT1_OFF; eW = e1W; eb = e1b; }
  else if (l == 2) { Hl = 32;  Cl = 256; fo = FT2_OFF; eW = e2W; eb = e2b; }
  else if (l == 3) { Hl = 16;  Cl = 512; fo = FT3_OFF; eW = e3W; eb = e3b; }
  else             { Hl = 16;  Cl = 256; fo = FT4_OFF; eW = e4W; eb = e4b; }
  int Wl = Hl;
  const float* ft = ftt + fo + (size_t)b * Hl * Wl * Cl;

  if (tid < 32) {
    float aw = wts[(size_t)t * 32 + tid];
    float px = poss[(size_t)t * 64 + tid * 2 + 0];
    float py = poss[(size_t)t * 64 + tid * 2 + 1];
    float gx = fminf(fmaxf((px + 1.0f) * 0.5f * (float)(Wl - 1), 0.0f), (float)(Wl - 1));
    float gy = fminf(fmaxf((py + 1.0f) * 0.5f * (float)(Hl - 1), 0.0f), (float)(Hl - 1));
    float x0f = floorf(gx), y0f = floorf(gy);
    int x0 = (int)x0f, y0 = (int)y0f;
    int x1 = min(x0 + 1, Wl - 1), y1 = min(y0 + 1, Hl - 1);
    float wx = gx - x0f, wy = gy - y0f;
    int base = tid * 4;
    hwid[base + 0] = y0 * Wl + x0; coef[base + 0] = aw * (1.f - wx) * (1.f - wy);
    hwid[base + 1] = y0 * Wl + x1; coef[base + 1] = aw * wx * (1.f - wy);
    hwid[base + 2] = y1 * Wl + x0; coef[base + 2] = aw * (1.f - wx) * wy;
    hwid[base + 3] = y1 * Wl + x1; coef[base + 3] = aw * wx * wy;
  }
  __syncthreads();

  int hh = tid >> 5;      // head 0..7
  int lane = tid & 31;
  // weighted combine over the head's 4 samples x 4 taps, in C_level space
  for (int c = lane; c < Cl; c += 32) {
    float acc = 0.f;
    #pragma unroll
    for (int k = 0; k < 16; k++)
      acc += coef[hh * 16 + k] * ft[(size_t)hwid[hh * 16 + k] * Cl + c];
    vbuf[hh * Cl + c] = acc;
  }
  __syncthreads();

  // project C_level -> 32 (softmax weights sum to 1, so bias passes through)
  int d = lane;
  float o = eb[d];
  for (int c = 0; c < Cl; c++) o += vbuf[hh * Cl + c] * eW[c * 32 + d];

  size_t xo = (((size_t)b * 6 + (l + 1)) * P_ + p) * C_ + hh * 32 + d;
  out[xo] = x[xo] + o;   // residual: xq2 = xq + attn_out
}

// LN2 + MLP (gelu exact) + residual, in place on d_out[:,1:].  grid: TOK x 256.
__global__ void ln2_mlp(float* __restrict__ out,
                        const float* __restrict__ g, const float* __restrict__ bt,
                        const float* __restrict__ f1W, const float* __restrict__ f1b,
                        const float* __restrict__ f2W, const float* __restrict__ f2b) {
  __shared__ float xq2[C_];
  __shared__ float h2[C_];
  __shared__ float u[2 * C_];
  __shared__ float red[C_];
  int t = blockIdx.x;
  int b = t / (L_ * P_);
  int r = t - b * (L_ * P_);
  int l = r / P_;
  int p = r - l * P_;
  int c = threadIdx.x;

  size_t o = (((size_t)b * 6 + (l + 1)) * P_ + p) * C_;
  float v = out[o + c];
  xq2[c] = v;

  float mean = block_sum256(v, red, c) * (1.0f / C_);
  float dv = v - mean;
  float var = block_sum256(dv * dv, red, c) * (1.0f / C_);
  h2[c] = dv * rsqrtf(var + 1e-5f) * g[c] + bt[c];
  __syncthreads();

  for (int j = c; j < 2 * C_; j += C_) {
    float acc = f1b[j];
    for (int i = 0; i < C_; i++) acc += h2[i] * f1W[i * (2 * C_) + j];
    u[j] = 0.5f * acc * (1.0f + erff(acc * 0.70710678118654752f));
  }
  __syncthreads();

  float acc = f2b[c];
  for (int j = 0; j < 2 * C_; j++) acc += u[j] * f2W[j * C_ + c];
  out[o + c] = xq2[c] + acc;
}

extern "C" void kernel_launch(void* const* d_in, const int* in_sizes, int n_in,
                              void* d_out, int out_size, void* d_ws, size_t ws_size,
                              hipStream_t stream) {
  const float* x     = (const float*)d_in[0];
  const float* ref   = (const float*)d_in[1];
  const float* feat0 = (const float*)d_in[2];
  const float* feat1 = (const float*)d_in[3];
  const float* feat2 = (const float*)d_in[4];
  const float* feat3 = (const float*)d_in[5];
  const float* feat4 = (const float*)d_in[6];
  const float* n1g   = (const float*)d_in[7];
  const float* n1b   = (const float*)d_in[8];
  const float* awW   = (const float*)d_in[9];
  const float* awb   = (const float*)d_in[10];
  const float* soW   = (const float*)d_in[11];
  const float* sob   = (const float*)d_in[12];
  const float* e0W   = (const float*)d_in[13];
  const float* e0b   = (const float*)d_in[14];
  const float* e1W   = (const float*)d_in[15];
  const float* e1b   = (const float*)d_in[16];
  const float* e2W   = (const float*)d_in[17];
  const float* e2b   = (const float*)d_in[18];
  const float* e3W   = (const float*)d_in[19];
  const float* e3b   = (const float*)d_in[20];
  const float* e4W   = (const float*)d_in[21];
  const float* e4b   = (const float*)d_in[22];
  const float* n2g   = (const float*)d_in[23];
  const float* n2b   = (const float*)d_in[24];
  const float* f1W   = (const float*)d_in[25];
  const float* f1b   = (const float*)d_in[26];
  const float* f2W   = (const float*)d_in[27];
  const float* f2b   = (const float*)d_in[28];

  float* ws   = (float*)d_ws;
  float* ftt  = ws;
  float* wts  = ws + WTS_OFF;
  float* poss = ws + POS_OFF;
  float* out  = (float*)d_out;

  // 1) transpose feature pyramids to (B,HW,C)
  transpose_feat<<<dim3(256, 2, B_), 256, 0, stream>>>(feat0, ftt + FT0_OFF, 64, 16384);
  transpose_feat<<<dim3(64, 4, B_), 256, 0, stream>>>(feat1, ftt + FT1_OFF, 128, 4096);
  transpose_feat<<<dim3(16, 8, B_), 256, 0, stream>>>(feat2, ftt + FT2_OFF, 256, 1024);
  transpose_feat<<<dim3(4, 16, B_), 256, 0, stream>>>(feat3, ftt + FT3_OFF, 512, 256);
  transpose_feat<<<dim3(4, 8, B_), 256, 0, stream>>>(feat4, ftt + FT4_OFF, 256, 256);

  // 2) passthrough token 0
  copy_x0<<<(B_ * P_ * C_) / 256, 256, 0, stream>>>(x, out);

  // 3) LN1 + attention weights + sampling positions
  ln1_awso<<<TOK, 256, 0, stream>>>(x, ref, n1g, n1b, awW, awb, soW, sob, wts, poss);

  // 4) sample + combine + project + residual -> out[:,1:]
  sample_proj<<<TOK, 256, 0, stream>>>(x, ftt, wts, poss,
                                       e0W, e0b, e1W, e1b, e2W, e2b, e3W, e3b, e4W, e4b,
                                       out);

  // 5) LN2 + MLP + residual, in place
  ln2_mlp<<<TOK, 256, 0, stream>>>(out, n2g, n2b, f1W, f1b, f2W, f2b);
}

// Round 2
// 779.035 us; speedup vs baseline: 1.7702x; 1.7702x over previous
//
#include <hip/hip_runtime.h>
#include <math.h>

#define B_ 4
#define L_ 5
#define P_ 1024
#define C_ 256
#define TOK (B_ * L_ * P_)   // 20480

// ---- workspace float offsets ----
// transposed feats (B,H,W,C):
#define FT0_OFF 0u
#define FT1_OFF 4194304u
#define FT2_OFF 6291456u
#define FT3_OFF 7340032u
#define FT4_OFF 7864320u
#define FT_TOTAL 8126464u
#define WTS_OFF  FT_TOTAL                 // TOK*32
#define POS_OFF  (FT_TOTAL + 655360u)     // TOK*64
// After sample_proj completes, the ftt region is dead; the bf16 GEMM scratch
// (h2, u, W1T, W2T) overlays it (ends at 7,995,392 floats < FT_TOTAL).

typedef short bf16x8 __attribute__((ext_vector_type(8)));
typedef float f32x4  __attribute__((ext_vector_type(4)));

__device__ __forceinline__ unsigned short f2bf(float f) {
  unsigned u = __float_as_uint(f);
  unsigned r = (u + 0x7fffu + ((u >> 16) & 1u)) >> 16;   // RNE
  return (unsigned short)r;
}

// block-wide sum over 256 threads; `red` is a 256-float LDS buffer
__device__ __forceinline__ float block_sum256(float v, float* red, int c) {
  red[c] = v; __syncthreads();
  for (int s = 128; s > 0; s >>= 1) {
    if (c < s) red[c] += red[c + s];
    __syncthreads();
  }
  float r = red[0];
  __syncthreads();
  return r;
}

// (B,C,HW) -> (B,HW,C) tiled transpose. grid: (HW/64, C/32, B), block 256.
__global__ void transpose_feat(const float* __restrict__ src, float* __restrict__ dst,
                               int C, int HW) {
  __shared__ float tile[32][65];
  int b = blockIdx.z;
  int hw0 = blockIdx.x * 64;
  int c0 = blockIdx.y * 32;
  const float* s = src + (size_t)b * C * HW;
  float* d = dst + (size_t)b * HW * C;
  int tw = threadIdx.x & 63;          // 0..63
  int tc = threadIdx.x >> 6;          // 0..3
  for (int cc = tc; cc < 32; cc += 4)
    tile[cc][tw] = s[(size_t)(c0 + cc) * HW + hw0 + tw];
  __syncthreads();
  int tcl = threadIdx.x & 31;         // 0..31
  int thw = threadIdx.x >> 5;         // 0..7
  for (int ww = thw; ww < 64; ww += 8)
    d[(size_t)(hw0 + ww) * C + c0 + tcl] = tile[tcl][ww];
}

// out[:,0,:,:] = x[:,0,:,:]
__global__ void copy_x0(const float* __restrict__ x, float* __restrict__ out) {
  int i = blockIdx.x * 256 + threadIdx.x;          // B*P*C total
  int b = i / (P_ * C_);
  int r = i - b * (P_ * C_);
  size_t off = (size_t)b * 6 * P_ * C_ + r;
  out[off] = x[off];
}

// LN1 + attention-weight scores (softmax over NS=4) + sampling offsets (tanh)+ref
// grid: TOK blocks x 256 threads
__global__ void ln1_awso(const float* __restrict__ x, const float* __restrict__ ref,
                         const float* __restrict__ g, const float* __restrict__ bt,
                         const float* __restrict__ awW, const float* __restrict__ awb,
                         const float* __restrict__ soW, const float* __restrict__ sob,
                         float* __restrict__ wts, float* __restrict__ poss) {
  __shared__ float h[C_];
  __shared__ float red[C_];
  __shared__ float sc[96];
  int t = blockIdx.x;
  int b = t / (L_ * P_);
  int r = t - b * (L_ * P_);
  int l = r / P_;
  int p = r - l * P_;
  int c = threadIdx.x;

  size_t xq_off = (((size_t)b * 6 + (l + 1)) * P_ + p) * C_;
  size_t x0_off = (((size_t)b * 6) * P_ + p) * C_;
  float v = x[xq_off + c] + x[x0_off + c];

  float mean = block_sum256(v, red, c) * (1.0f / C_);
  float dv = v - mean;
  float var = block_sum256(dv * dv, red, c) * (1.0f / C_);
  h[c] = dv * rsqrtf(var + 1e-5f) * g[c] + bt[c];
  __syncthreads();

  if (c < 32) {
    float acc = awb[c];
    for (int i = 0; i < C_; i++) acc += h[i] * awW[i * 32 + c];
    sc[c] = acc;
  } else if (c < 96) {
    int j = c - 32;
    float acc = sob[j];
    for (int i = 0; i < C_; i++) acc += h[i] * soW[i * 64 + j];
    sc[c] = acc;
  }
  __syncthreads();

  if (c < 32) {
    int hh = c >> 2;
    float m = sc[hh * 4];
    for (int k = 1; k < 4; k++) m = fmaxf(m, sc[hh * 4 + k]);
    float den = 0.f;
    for (int k = 0; k < 4; k++) den += expf(sc[hh * 4 + k] - m);
    wts[(size_t)t * 32 + c] = expf(sc[c] - m) / den;
  } else if (c < 96) {
    int j = c - 32;
    int coord = j & 1;
    float pv = tanhf(sc[c]) + ref[((size_t)b * P_ + p) * 2 + coord];
    poss[(size_t)t * 64 + j] = pv;
  }
}

// bilinear sample (border clamp) + weighted combine over NS + per-level projection
// + residual.  Writes xq2 into d_out[:,1+l].  grid: TOK x 256 threads.
__global__ void sample_proj(const float* __restrict__ x, const float* __restrict__ ftt,
                            const float* __restrict__ wts, const float* __restrict__ poss,
                            const float* __restrict__ e0W, const float* __restrict__ e0b,
                            const float* __restrict__ e1W, const float* __restrict__ e1b,
                            const float* __restrict__ e2W, const float* __restrict__ e2b,
                            const float* __restrict__ e3W, const float* __restrict__ e3b,
                            const float* __restrict__ e4W, const float* __restrict__ e4b,
                            float* __restrict__ out) {
  __shared__ float coef[128];
  __shared__ int   hwid[128];
  __shared__ float vbuf[8 * 512];   // 16 KB max (level 3: C=512)
  int t = blockIdx.x;
  int b = t / (L_ * P_);
  int r = t - b * (L_ * P_);
  int l = r / P_;
  int p = r - l * P_;
  int tid = threadIdx.x;

  int Hl, Cl; size_t fo; const float* eW; const float* eb;
  if (l == 0)      { Hl = 128; Cl = 64;  fo = FT0_OFF; eW = e0W; eb = e0b; }
  else if (l == 1) { Hl = 64;  Cl = 128; fo = FT1_OFF; eW = e1W; eb = e1b; }
  else if (l == 2) { Hl = 32;  Cl = 256; fo = FT2_OFF; eW = e2W; eb = e2b; }
  else if (l == 3) { Hl = 16;  Cl = 512; fo = FT3_OFF; eW = e3W; eb = e3b; }
  else             { Hl = 16;  Cl = 256; fo = FT4_OFF; eW = e4W; eb = e4b; }
  int Wl = Hl;
  const float* ft = ftt + fo + (size_t)b * Hl * Wl * Cl;

  if (tid < 32) {
    float aw = wts[(size_t)t * 32 + tid];
    float px = poss[(size_t)t * 64 + tid * 2 + 0];
    float py = poss[(size_t)t * 64 + tid * 2 + 1];
    float gx = fminf(fmaxf((px + 1.0f) * 0.5f * (float)(Wl - 1), 0.0f), (float)(Wl - 1));
    float gy = fminf(fmaxf((py + 1.0f) * 0.5f * (float)(Hl - 1), 0.0f), (float)(Hl - 1));
    float x0f = floorf(gx), y0f = floorf(gy);
    int x0 = (int)x0f, y0 = (int)y0f;
    int x1 = min(x0 + 1, Wl - 1), y1 = min(y0 + 1, Hl - 1);
    float wx = gx - x0f, wy = gy - y0f;
    int base = tid * 4;
    hwid[base + 0] = y0 * Wl + x0; coef[base + 0] = aw * (1.f - wx) * (1.f - wy);
    hwid[base + 1] = y0 * Wl + x1; coef[base + 1] = aw * wx * (1.f - wy);
    hwid[base + 2] = y1 * Wl + x0; coef[base + 2] = aw * (1.f - wx) * wy;
    hwid[base + 3] = y1 * Wl + x1; coef[base + 3] = aw * wx * wy;
  }
  __syncthreads();

  int hh = tid >> 5;      // head 0..7
  int lane = tid & 31;
  // weighted combine over the head's 4 samples x 4 taps, in C_level space
  for (int c = lane; c < Cl; c += 32) {
    float acc = 0.f;
    #pragma unroll
    for (int k = 0; k < 16; k++)
      acc += coef[hh * 16 + k] * ft[(size_t)hwid[hh * 16 + k] * Cl + c];
    vbuf[hh * Cl + c] = acc;
  }
  __syncthreads();

  // project C_level -> 32 (softmax weights sum to 1, so bias passes through)
  int d = lane;
  float o = eb[d];
  for (int c = 0; c < Cl; c++) o += vbuf[hh * Cl + c] * eW[c * 32 + d];

  size_t xo = (((size_t)b * 6 + (l + 1)) * P_ + p) * C_ + hh * 32 + d;
  out[xo] = x[xo] + o;   // residual: xq2 = xq + attn_out
}

// LN2 only: reads xq2 from d_out[:,1:], writes normalized bf16 h2 (TOK x 256).
__global__ void ln2_h(const float* __restrict__ out,
                      const float* __restrict__ g, const float* __restrict__ bt,
                      unsigned short* __restrict__ h2) {
  __shared__ float red[C_];
  int t = blockIdx.x;
  int b = t / (L_ * P_);
  int r = t - b * (L_ * P_);
  int l = r / P_;
  int p = r - l * P_;
  int c = threadIdx.x;

  size_t o = (((size_t)b * 6 + (l + 1)) * P_ + p) * C_;
  float v = out[o + c];
  float mean = block_sum256(v, red, c) * (1.0f / C_);
  float dv = v - mean;
  float var = block_sum256(dv * dv, red, c) * (1.0f / C_);
  float h = dv * rsqrtf(var + 1e-5f) * g[c] + bt[c];
  h2[(size_t)t * C_ + c] = f2bf(h);
}

// fc1/fc2 weights -> bf16, transposed to (N,K) K-contiguous.
__global__ void prep_w(const float* __restrict__ f1W, const float* __restrict__ f2W,
                       unsigned short* __restrict__ W1T, unsigned short* __restrict__ W2T) {
  int i = blockIdx.x * 256 + threadIdx.x;     // 262144 total
  if (i < 131072) {            // W1: (K=256, N=512) -> W1T[n*256+k]
    int n = i >> 8, k = i & 255;
    W1T[i] = f2bf(f1W[k * 512 + n]);
  } else {                     // W2: (K=512, N=256) -> W2T[n*512+k]
    int j = i - 131072;
    int n = j >> 9, k = j & 511;
    W2T[j] = f2bf(f2W[k * 256 + n]);
  }
}

// bf16 MFMA GEMM, 64x64 tile, BK=64.  A: (M,K) bf16 row-major.  Bt: (N,K) bf16.
// MODE 0: outU[m*N+n] = bf16(gelu(acc + bias[n]))
// MODE 1: outF[remap(m)*256 + n] += acc + bias[n]   (residual add into d_out)
template<int MODE>
__global__ __launch_bounds__(256) void gemm_bf16(
    const unsigned short* __restrict__ A, const unsigned short* __restrict__ Bt,
    const float* __restrict__ bias, unsigned short* __restrict__ outU,
    float* __restrict__ outF, int N, int K) {
  constexpr int LDK = 72;                 // 64 + 8 pad: 4-bank rotate per row -> 2-way (free)
  __shared__ unsigned short Al[64 * LDK];
  __shared__ unsigned short Bl[64 * LDK];
  int m0 = blockIdx.x * 64, n0 = blockIdx.y * 64;
  int tid = threadIdx.x;
  int w = tid >> 6, lane = tid & 63;
  int q = lane >> 4, ml = lane & 15;
  int lr = tid >> 3;                      // 0..31 (row within half-tile)
  int lk = (tid & 7) * 8;                 // k offset (shorts)

  f32x4 acc[4];
  #pragma unroll
  for (int i = 0; i < 4; i++) acc[i] = (f32x4){0.f, 0.f, 0.f, 0.f};

  for (int k0 = 0; k0 < K; k0 += 64) {
    int4 a0 = *(const int4*)(A + (size_t)(m0 + lr) * K + k0 + lk);
    int4 a1 = *(const int4*)(A + (size_t)(m0 + 32 + lr) * K + k0 + lk);
    int4 b0 = *(const int4*)(Bt + (size_t)(n0 + lr) * K + k0 + lk);
    int4 b1 = *(const int4*)(Bt + (size_t)(n0 + 32 + lr) * K + k0 + lk);
    __syncthreads();
    *(int4*)(Al + lr * LDK + lk) = a0;
    *(int4*)(Al + (32 + lr) * LDK + lk) = a1;
    *(int4*)(Bl + lr * LDK + lk) = b0;
    *(int4*)(Bl + (32 + lr) * LDK + lk) = b1;
    __syncthreads();
    #pragma unroll
    for (int ks = 0; ks < 2; ks++) {
      bf16x8 af = *(const bf16x8*)(Al + (w * 16 + ml) * LDK + ks * 32 + q * 8);
      #pragma unroll
      for (int nt = 0; nt < 4; nt++) {
        bf16x8 bf = *(const bf16x8*)(Bl + (nt * 16 + ml) * LDK + ks * 32 + q * 8);
        acc[nt] = __builtin_amdgcn_mfma_f32_16x16x32_bf16(af, bf, acc[nt], 0, 0, 0);
      }
    }
  }

  #pragma unroll
  for (int nt = 0; nt < 4; nt++) {
    int n = n0 + nt * 16 + ml;
    float bv = bias[n];
    #pragma unroll
    for (int rr = 0; rr < 4; rr++) {
      int m = m0 + w * 16 + q * 4 + rr;
      float v = acc[nt][rr] + bv;
      if (MODE == 0) {
        v = 0.5f * v * (1.0f + erff(v * 0.70710678118654752f));
        outU[(size_t)m * N + n] = f2bf(v);
      } else {
        int s = m >> 10;                  // slab = b*5 + l  (64-row tile never crosses)
        int p = m & 1023;
        int bb = s / 5, ll = s - bb * 5;
        size_t o = (((size_t)bb * 6 + ll + 1) * P_ + p) * C_ + n;
        outF[o] += v;
      }
    }
  }
}

extern "C" void kernel_launch(void* const* d_in, const int* in_sizes, int n_in,
                              void* d_out, int out_size, void* d_ws, size_t ws_size,
                              hipStream_t stream) {
  const float* x     = (const float*)d_in[0];
  const float* ref   = (const float*)d_in[1];
  const float* feat0 = (const float*)d_in[2];
  const float* feat1 = (const float*)d_in[3];
  const float* feat2 = (const float*)d_in[4];
  const float* feat3 = (const float*)d_in[5];
  const float* feat4 = (const float*)d_in[6];
  const float* n1g   = (const float*)d_in[7];
  const float* n1b   = (const float*)d_in[8];
  const float* awW   = (const float*)d_in[9];
  const float* awb   = (const float*)d_in[10];
  const float* soW   = (const float*)d_in[11];
  const float* sob   = (const float*)d_in[12];
  const float* e0W   = (const float*)d_in[13];
  const float* e0b   = (const float*)d_in[14];
  const float* e1W   = (const float*)d_in[15];
  const float* e1b   = (const float*)d_in[16];
  const float* e2W   = (const float*)d_in[17];
  const float* e2b   = (const float*)d_in[18];
  const float* e3W   = (const float*)d_in[19];
  const float* e3b   = (const float*)d_in[20];
  const float* e4W   = (const float*)d_in[21];
  const float* e4b   = (const float*)d_in[22];
  const float* n2g   = (const float*)d_in[23];
  const float* n2b   = (const float*)d_in[24];
  const float* f1W   = (const float*)d_in[25];
  const float* f1b   = (const float*)d_in[26];
  const float* f2W   = (const float*)d_in[27];
  const float* f2b   = (const float*)d_in[28];

  float* ws   = (float*)d_ws;
  float* ftt  = ws;
  float* wts  = ws + WTS_OFF;
  float* poss = ws + POS_OFF;
  float* out  = (float*)d_out;

  // bf16 GEMM scratch overlays ftt (dead after sample_proj; stream is serial)
  unsigned short* h2  = (unsigned short*)d_ws;            // TOK*256
  unsigned short* u   = h2 + (size_t)TOK * 256;           // TOK*512
  unsigned short* W1T = u + (size_t)TOK * 512;            // 512*256
  unsigned short* W2T = W1T + 512 * 256;                  // 256*512

  // 1) transpose feature pyramids to (B,HW,C)
  transpose_feat<<<dim3(256, 2, B_), 256, 0, stream>>>(feat0, ftt + FT0_OFF, 64, 16384);
  transpose_feat<<<dim3(64, 4, B_), 256, 0, stream>>>(feat1, ftt + FT1_OFF, 128, 4096);
  transpose_feat<<<dim3(16, 8, B_), 256, 0, stream>>>(feat2, ftt + FT2_OFF, 256, 1024);
  transpose_feat<<<dim3(4, 16, B_), 256, 0, stream>>>(feat3, ftt + FT3_OFF, 512, 256);
  transpose_feat<<<dim3(4, 8, B_), 256, 0, stream>>>(feat4, ftt + FT4_OFF, 256, 256);

  // 2) passthrough token 0
  copy_x0<<<(B_ * P_ * C_) / 256, 256, 0, stream>>>(x, out);

  // 3) LN1 + attention weights + sampling positions
  ln1_awso<<<TOK, 256, 0, stream>>>(x, ref, n1g, n1b, awW, awb, soW, sob, wts, poss);

  // 4) sample + combine + project + residual -> out[:,1:]
  sample_proj<<<TOK, 256, 0, stream>>>(x, ftt, wts, poss,
                                       e0W, e0b, e1W, e1b, e2W, e2b, e3W, e3b, e4W, e4b,
                                       out);

  // 5) weights -> bf16 transposed (after sample_proj: overlays ftt)
  prep_w<<<1024, 256, 0, stream>>>(f1W, f2W, W1T, W2T);

  // 6) LN2 -> h2 bf16
  ln2_h<<<TOK, 256, 0, stream>>>(out, n2g, n2b, h2);

  // 7) MLP GEMM1: u = gelu(h2 @ W1 + b1)        M=20480 N=512 K=256
  gemm_bf16<0><<<dim3(320, 8), 256, 0, stream>>>(h2, W1T, f1b, u, nullptr, 512, 256);

  // 8) MLP GEMM2: out += u @ W2 + b2            M=20480 N=256 K=512
  gemm_bf16<1><<<dim3(320, 4), 256, 0, stream>>>(u, W2T, f2b, nullptr, out, 256, 512);
}

// Round 3
// 348.386 us; speedup vs baseline: 3.9584x; 2.2361x over previous
//
#include <hip/hip_runtime.h>
#include <math.h>

#define B_ 4
#define L_ 5
#define P_ 1024
#define C_ 256
#define TOK (B_ * L_ * P_)   // 20480

// ---- transposed feats (B,H,W,C) bf16, short-index offsets ----
#define FT0_OFF 0u
#define FT1_OFF 4194304u
#define FT2_OFF 6291456u
#define FT3_OFF 7340032u
#define FT4_OFF 7864320u
// ---- workspace layout (byte-planned, ~39.2 MB total; proven budget 40.3 MB) ----
#define WTS_F   4063232u     // float index: TOK*32
#define POSS_F  4718592u     // float index: TOK*64
#define H1_S    12058624u    // short index: TOK*256 (reused as h2 for MLP)
#define S_S     17301504u    // short index: TOK*96 scores bf16
#define WC_S    19267584u    // short index: 96*256
#define EWT_S   19292160u    // short index: 32*(64+128+256+512+256)=38912
#define W1T_S   19331072u    // short index: 512*256
#define W2T_S   19462144u    // short index: 256*512
#define BCAT_F  9796608u     // float index: 96
// u (TOK*512 shorts = 20.97 MB) overlays offset 0 (ftt+wts+poss dead by then)

typedef short bf16x8 __attribute__((ext_vector_type(8)));
typedef float f32x4  __attribute__((ext_vector_type(4)));

__device__ __forceinline__ unsigned short f2bf(float f) {
  unsigned u = __float_as_uint(f);
  unsigned r = (u + 0x7fffu + ((u >> 16) & 1u)) >> 16;   // RNE
  return (unsigned short)r;
}
__device__ __forceinline__ float bf2f(unsigned short u) {
  return __uint_as_float((unsigned)u << 16);
}

__device__ __forceinline__ float block_sum256(float v, float* red, int c) {
  red[c] = v; __syncthreads();
  for (int s = 128; s > 0; s >>= 1) {
    if (c < s) red[c] += red[c + s];
    __syncthreads();
  }
  float r = red[0];
  __syncthreads();
  return r;
}

// (B,C,HW) fp32 -> (B,HW,C) bf16. grid: (HW/64, C/32, B), block 256.
__global__ void transpose_feat(const float* __restrict__ src, unsigned short* __restrict__ dst,
                               int C, int HW) {
  __shared__ float tile[32][65];
  int b = blockIdx.z;
  int hw0 = blockIdx.x * 64;
  int c0 = blockIdx.y * 32;
  const float* s = src + (size_t)b * C * HW;
  unsigned short* d = dst + (size_t)b * HW * C;
  int tw = threadIdx.x & 63;
  int tc = threadIdx.x >> 6;
  for (int cc = tc; cc < 32; cc += 4)
    tile[cc][tw] = s[(size_t)(c0 + cc) * HW + hw0 + tw];
  __syncthreads();
  int tcl = threadIdx.x & 31;
  int thw = threadIdx.x >> 5;
  for (int ww = thw; ww < 64; ww += 8)
    d[(size_t)(hw0 + ww) * C + c0 + tcl] = f2bf(tile[tcl][ww]);
}

__global__ void copy_x0(const float* __restrict__ x, float* __restrict__ out) {
  int i = blockIdx.x * 256 + threadIdx.x;
  int b = i / (P_ * C_);
  int r = i - b * (P_ * C_);
  size_t off = (size_t)b * 6 * P_ * C_ + r;
  out[off] = x[off];
}

// LN1 over (xq + x0) -> h1 bf16.  grid TOK x 256.
__global__ void ln1_h(const float* __restrict__ x,
                      const float* __restrict__ g, const float* __restrict__ bt,
                      unsigned short* __restrict__ h1) {
  __shared__ float red[C_];
  int t = blockIdx.x;
  int b = t / (L_ * P_);
  int r = t - b * (L_ * P_);
  int l = r / P_;
  int p = r - l * P_;
  int c = threadIdx.x;
  size_t xq_off = (((size_t)b * 6 + (l + 1)) * P_ + p) * C_;
  size_t x0_off = (((size_t)b * 6) * P_ + p) * C_;
  float v = x[xq_off + c] + x[x0_off + c];
  float mean = block_sum256(v, red, c) * (1.0f / C_);
  float dv = v - mean;
  float var = block_sum256(dv * dv, red, c) * (1.0f / C_);
  float h = dv * rsqrtf(var + 1e-5f) * g[c] + bt[c];
  h1[(size_t)t * C_ + c] = f2bf(h);
}

// LN2 over xq2 (from d_out[:,1:]) -> h2 bf16 (reuses h1 buffer).  grid TOK x 256.
__global__ void ln2_h(const float* __restrict__ out,
                      const float* __restrict__ g, const float* __restrict__ bt,
                      unsigned short* __restrict__ h2) {
  __shared__ float red[C_];
  int t = blockIdx.x;
  int b = t / (L_ * P_);
  int r = t - b * (L_ * P_);
  int l = r / P_;
  int p = r - l * P_;
  int c = threadIdx.x;
  size_t o = (((size_t)b * 6 + (l + 1)) * P_ + p) * C_;
  float v = out[o + c];
  float mean = block_sum256(v, red, c) * (1.0f / C_);
  float dv = v - mean;
  float var = block_sum256(dv * dv, red, c) * (1.0f / C_);
  float h = dv * rsqrtf(var + 1e-5f) * g[c] + bt[c];
  h2[(size_t)t * C_ + c] = f2bf(h);
}

// All weight prep: W1T, W2T, Wc (96x256), eWT (32xCl per level), bcat (96 fp32).
__global__ void prep_all(const float* __restrict__ f1W, const float* __restrict__ f2W,
                         const float* __restrict__ awW, const float* __restrict__ soW,
                         const float* __restrict__ awb, const float* __restrict__ sob,
                         const float* __restrict__ e0W, const float* __restrict__ e1W,
                         const float* __restrict__ e2W, const float* __restrict__ e3W,
                         const float* __restrict__ e4W,
                         unsigned short* __restrict__ W1T, unsigned short* __restrict__ W2T,
                         unsigned short* __restrict__ Wc, unsigned short* __restrict__ eWT,
                         float* __restrict__ bcat) {
  int i = blockIdx.x * 256 + threadIdx.x;
  if (i < 131072) {                       // W1T[n*256+k] = f1W[k*512+n]
    int n = i >> 8, k = i & 255;
    W1T[i] = f2bf(f1W[k * 512 + n]);
  } else if (i < 262144) {                // W2T[n*512+k] = f2W[k*256+n]
    int j = i - 131072;
    int n = j >> 9, k = j & 511;
    W2T[j] = f2bf(f2W[k * 256 + n]);
  } else if (i < 286720) {                // Wc[n*256+k]
    int j = i - 262144;
    int n = j >> 8, k = j & 255;
    Wc[j] = f2bf(n < 32 ? awW[k * 32 + n] : soW[k * 64 + (n - 32)]);
  } else if (i < 325632) {                // eWT
    int j = i - 286720;
    const float* eW; int Cl, base, jj;
    if (j < 2048)       { eW = e0W; Cl = 64;  base = 0;     jj = j; }
    else if (j < 6144)  { eW = e1W; Cl = 128; base = 2048;  jj = j - 2048; }
    else if (j < 14336) { eW = e2W; Cl = 256; base = 6144;  jj = j - 6144; }
    else if (j < 30720) { eW = e3W; Cl = 512; base = 14336; jj = j - 14336; }
    else                { eW = e4W; Cl = 256; base = 30720; jj = j - 30720; }
    int d = jj / Cl, c = jj & (Cl - 1);
    eWT[base + jj] = f2bf(eW[c * 32 + d]);
  } else if (i < 325728) {
    int j = i - 325632;
    bcat[j] = j < 32 ? awb[j] : sob[j - 32];
  }
}

// softmax over NS=4 -> wts; tanh + ref -> poss.  grid TOK x 128.
__global__ void postproc(const unsigned short* __restrict__ S, const float* __restrict__ ref,
                         float* __restrict__ wts, float* __restrict__ poss) {
  int t = blockIdx.x;
  int c = threadIdx.x;
  int b = t / (L_ * P_);
  int p = t & (P_ - 1);
  if (c < 32) {
    int g4 = (c >> 2) << 2;
    float s0 = bf2f(S[(size_t)t * 96 + g4 + 0]);
    float s1 = bf2f(S[(size_t)t * 96 + g4 + 1]);
    float s2 = bf2f(S[(size_t)t * 96 + g4 + 2]);
    float s3 = bf2f(S[(size_t)t * 96 + g4 + 3]);
    float m = fmaxf(fmaxf(s0, s1), fmaxf(s2, s3));
    float den = expf(s0 - m) + expf(s1 - m) + expf(s2 - m) + expf(s3 - m);
    float sc = bf2f(S[(size_t)t * 96 + c]);
    wts[(size_t)t * 32 + c] = expf(sc - m) / den;
  } else if (c < 96) {
    int j = c - 32;
    float sv = bf2f(S[(size_t)t * 96 + 32 + j]);
    poss[(size_t)t * 64 + j] = tanhf(sv) + ref[((size_t)b * P_ + p) * 2 + (j & 1)];
  }
}

// bf16 MFMA GEMM, 64x64 tile, BK=64, N-guarded.  A:(M,K) bf16.  Bt:(N,K) bf16.
// MODE 0: outU = bf16(gelu(acc+bias))   MODE 1: outF[remap] += acc+bias
// MODE 2: outU = bf16(acc+bias)
template<int MODE>
__global__ __launch_bounds__(256) void gemm_bf16(
    const unsigned short* __restrict__ A, const unsigned short* __restrict__ Bt,
    const float* __restrict__ bias, unsigned short* __restrict__ outU,
    float* __restrict__ outF, int N, int K) {
  constexpr int LDK = 72;
  __shared__ unsigned short Al[64 * LDK];
  __shared__ unsigned short Bl[64 * LDK];
  int m0 = blockIdx.x * 64, n0 = blockIdx.y * 64;
  int tid = threadIdx.x;
  int w = tid >> 6, lane = tid & 63;
  int q = lane >> 4, ml = lane & 15;
  int lr = tid >> 3;
  int lk = (tid & 7) * 8;

  f32x4 acc[4];
  #pragma unroll
  for (int i = 0; i < 4; i++) acc[i] = (f32x4){0.f, 0.f, 0.f, 0.f};

  int nr0 = min(n0 + lr, N - 1);
  int nr1 = min(n0 + 32 + lr, N - 1);

  for (int k0 = 0; k0 < K; k0 += 64) {
    int4 a0 = *(const int4*)(A + (size_t)(m0 + lr) * K + k0 + lk);
    int4 a1 = *(const int4*)(A + (size_t)(m0 + 32 + lr) * K + k0 + lk);
    int4 b0 = *(const int4*)(Bt + (size_t)nr0 * K + k0 + lk);
    int4 b1 = *(const int4*)(Bt + (size_t)nr1 * K + k0 + lk);
    __syncthreads();
    *(int4*)(Al + lr * LDK + lk) = a0;
    *(int4*)(Al + (32 + lr) * LDK + lk) = a1;
    *(int4*)(Bl + lr * LDK + lk) = b0;
    *(int4*)(Bl + (32 + lr) * LDK + lk) = b1;
    __syncthreads();
    #pragma unroll
    for (int ks = 0; ks < 2; ks++) {
      bf16x8 af = *(const bf16x8*)(Al + (w * 16 + ml) * LDK + ks * 32 + q * 8);
      #pragma unroll
      for (int nt = 0; nt < 4; nt++) {
        bf16x8 bf = *(const bf16x8*)(Bl + (nt * 16 + ml) * LDK + ks * 32 + q * 8);
        acc[nt] = __builtin_amdgcn_mfma_f32_16x16x32_bf16(af, bf, acc[nt], 0, 0, 0);
      }
    }
  }

  #pragma unroll
  for (int nt = 0; nt < 4; nt++) {
    int n = n0 + nt * 16 + ml;
    if (n >= N) continue;
    float bv = bias[n];
    #pragma unroll
    for (int rr = 0; rr < 4; rr++) {
      int m = m0 + w * 16 + q * 4 + rr;
      float v = acc[nt][rr] + bv;
      if (MODE == 0) {
        v = 0.5f * v * (1.0f + erff(v * 0.70710678118654752f));
        outU[(size_t)m * N + n] = f2bf(v);
      } else if (MODE == 2) {
        outU[(size_t)m * N + n] = f2bf(v);
      } else {
        int s = m >> 10;
        int p = m & 1023;
        int bb = s / 5, ll = s - bb * 5;
        size_t o = (((size_t)bb * 6 + ll + 1) * P_ + p) * C_ + n;
        outF[o] += v;
      }
    }
  }
}

// Fused gather + projection MFMA GEMM + residual.
// grid (512, 5): blockIdx.y = level, blockIdx.x = tile of 8 tokens (64 rows = 8tok x 8head).
__global__ __launch_bounds__(256) void samp_gemm(
    const float* __restrict__ x, const unsigned short* __restrict__ ftt,
    const float* __restrict__ wts, const float* __restrict__ poss,
    const unsigned short* __restrict__ eWT,
    const float* __restrict__ e0b, const float* __restrict__ e1b,
    const float* __restrict__ e2b, const float* __restrict__ e3b,
    const float* __restrict__ e4b,
    float* __restrict__ out) {
  __shared__ float coef[1024];
  __shared__ int   hwid[1024];
  __shared__ unsigned short Al[64 * 72];   // 64 rows x BK=64 (+8 pad)
  __shared__ unsigned short Bl[32 * 72];   // 32 cols x BK=64

  int l = blockIdx.y;
  int tile = blockIdx.x;
  int tid = threadIdx.x;

  int Hl, Cl; unsigned fo, eo; const float* eb;
  if (l == 0)      { Hl = 128; Cl = 64;  fo = FT0_OFF; eo = 0;     eb = e0b; }
  else if (l == 1) { Hl = 64;  Cl = 128; fo = FT1_OFF; eo = 2048;  eb = e1b; }
  else if (l == 2) { Hl = 32;  Cl = 256; fo = FT2_OFF; eo = 6144;  eb = e2b; }
  else if (l == 3) { Hl = 16;  Cl = 512; fo = FT3_OFF; eo = 14336; eb = e3b; }
  else             { Hl = 16;  Cl = 256; fo = FT4_OFF; eo = 30720; eb = e4b; }

  // phase 1: bilinear coefficients for 8 tokens x 32 samples
  {
    int tl = tid >> 5, s = tid & 31;
    int t_l = tile * 8 + tl;
    int b = t_l >> 10, p = t_l & 1023;
    int t = b * (L_ * P_) + l * P_ + p;
    float aw = wts[(size_t)t * 32 + s];
    float px = poss[(size_t)t * 64 + s * 2 + 0];
    float py = poss[(size_t)t * 64 + s * 2 + 1];
    float Wm = (float)(Hl - 1);
    float gx = fminf(fmaxf((px + 1.0f) * 0.5f * Wm, 0.0f), Wm);
    float gy = fminf(fmaxf((py + 1.0f) * 0.5f * Wm, 0.0f), Wm);
    float x0f = floorf(gx), y0f = floorf(gy);
    int x0 = (int)x0f, y0 = (int)y0f;
    int x1 = min(x0 + 1, Hl - 1), y1 = min(y0 + 1, Hl - 1);
    float wx = gx - x0f, wy = gy - y0f;
    int base = tid * 4;   // == tl*128 + s*4
    hwid[base + 0] = y0 * Hl + x0; coef[base + 0] = aw * (1.f - wx) * (1.f - wy);
    hwid[base + 1] = y0 * Hl + x1; coef[base + 1] = aw * wx * (1.f - wy);
    hwid[base + 2] = y1 * Hl + x0; coef[base + 2] = aw * (1.f - wx) * wy;
    hwid[base + 3] = y1 * Hl + x1; coef[base + 3] = aw * wx * wy;
  }
  __syncthreads();

  f32x4 acc0 = (f32x4){0.f, 0.f, 0.f, 0.f};
  f32x4 acc1 = (f32x4){0.f, 0.f, 0.f, 0.f};
  int w = tid >> 6, lane = tid & 63, q = lane >> 4, ml = lane & 15;
  const unsigned short* ew = eWT + eo;

  for (int k0 = 0; k0 < Cl; k0 += 64) {
    if (k0) __syncthreads();
    // stage B chunk: 32 x 64
    {
      int r = tid >> 3, kc = (tid & 7) * 8;
      *(int4*)(Bl + r * 72 + kc) = *(const int4*)(ew + (size_t)r * Cl + k0 + kc);
    }
    // gather A chunk: 64 rows x 16 groups of 4 channels
    #pragma unroll
    for (int it = 0; it < 4; it++) {
      int item = tid + 256 * it;
      int r = item >> 4, c4 = item & 15;
      int tl = r >> 3, h = r & 7;
      int b = (tile * 8 + tl) >> 10;
      const unsigned short* ft = ftt + fo + (size_t)b * (Hl * Hl) * Cl + k0 + c4 * 4;
      int cb = tl * 128 + h * 16;
      float a0 = 0.f, a1 = 0.f, a2 = 0.f, a3 = 0.f;
      #pragma unroll
      for (int k = 0; k < 16; k++) {
        float cf = coef[cb + k];
        ushort4 uv = *(const ushort4*)(ft + (size_t)hwid[cb + k] * Cl);
        a0 += cf * bf2f(uv.x);
        a1 += cf * bf2f(uv.y);
        a2 += cf * bf2f(uv.z);
        a3 += cf * bf2f(uv.w);
      }
      ushort4 st = { f2bf(a0), f2bf(a1), f2bf(a2), f2bf(a3) };
      *(ushort4*)(Al + r * 72 + c4 * 4) = st;
    }
    __syncthreads();
    #pragma unroll
    for (int ks = 0; ks < 2; ks++) {
      bf16x8 af = *(const bf16x8*)(Al + (w * 16 + ml) * 72 + ks * 32 + q * 8);
      bf16x8 b0 = *(const bf16x8*)(Bl + ml * 72 + ks * 32 + q * 8);
      bf16x8 b1 = *(const bf16x8*)(Bl + (16 + ml) * 72 + ks * 32 + q * 8);
      acc0 = __builtin_amdgcn_mfma_f32_16x16x32_bf16(af, b0, acc0, 0, 0, 0);
      acc1 = __builtin_amdgcn_mfma_f32_16x16x32_bf16(af, b1, acc1, 0, 0, 0);
    }
  }

  // epilogue: out = x + proj + bias
  #pragma unroll
  for (int nt = 0; nt < 2; nt++) {
    f32x4 a = nt ? acc1 : acc0;
    int col = nt * 16 + ml;
    float bv = eb[col];
    #pragma unroll
    for (int rr = 0; rr < 4; rr++) {
      int r = w * 16 + q * 4 + rr;
      int tl = r >> 3, h = r & 7;
      int t_l = tile * 8 + tl;
      int b = t_l >> 10, p = t_l & 1023;
      size_t o = (((size_t)b * 6 + l + 1) * P_ + p) * C_ + h * 32 + col;
      out[o] = x[o] + a[rr] + bv;
    }
  }
}

extern "C" void kernel_launch(void* const* d_in, const int* in_sizes, int n_in,
                              void* d_out, int out_size, void* d_ws, size_t ws_size,
                              hipStream_t stream) {
  const float* x     = (const float*)d_in[0];
  const float* ref   = (const float*)d_in[1];
  const float* feat0 = (const float*)d_in[2];
  const float* feat1 = (const float*)d_in[3];
  const float* feat2 = (const float*)d_in[4];
  const float* feat3 = (const float*)d_in[5];
  const float* feat4 = (const float*)d_in[6];
  const float* n1g   = (const float*)d_in[7];
  const float* n1b   = (const float*)d_in[8];
  const float* awW   = (const float*)d_in[9];
  const float* awb   = (const float*)d_in[10];
  const float* soW   = (const float*)d_in[11];
  const float* sob   = (const float*)d_in[12];
  const float* e0W   = (const float*)d_in[13];
  const float* e0b   = (const float*)d_in[14];
  const float* e1W   = (const float*)d_in[15];
  const float* e1b   = (const float*)d_in[16];
  const float* e2W   = (const float*)d_in[17];
  const float* e2b   = (const float*)d_in[18];
  const float* e3W   = (const float*)d_in[19];
  const float* e3b   = (const float*)d_in[20];
  const float* e4W   = (const float*)d_in[21];
  const float* e4b   = (const float*)d_in[22];
  const float* n2g   = (const float*)d_in[23];
  const float* n2b   = (const float*)d_in[24];
  const float* f1W   = (const float*)d_in[25];
  const float* f1b   = (const float*)d_in[26];
  const float* f2W   = (const float*)d_in[27];
  const float* f2b   = (const float*)d_in[28];

  float* wsf = (float*)d_ws;
  unsigned short* ws16 = (unsigned short*)d_ws;
  unsigned short* ftt  = ws16;
  float* wts  = wsf + WTS_F;
  float* poss = wsf + POSS_F;
  unsigned short* h1  = ws16 + H1_S;   // also h2 for MLP
  unsigned short* S   = ws16 + S_S;
  unsigned short* Wc  = ws16 + WC_S;
  unsigned short* eWT = ws16 + EWT_S;
  unsigned short* W1T = ws16 + W1T_S;
  unsigned short* W2T = ws16 + W2T_S;
  float* bcat = wsf + BCAT_F;
  unsigned short* u   = ws16;          // overlay (ftt/wts/poss dead)
  float* out = (float*)d_out;

  // 1) feature pyramids -> (B,HW,C) bf16
  transpose_feat<<<dim3(256, 2, B_), 256, 0, stream>>>(feat0, ftt + FT0_OFF, 64, 16384);
  transpose_feat<<<dim3(64, 4, B_), 256, 0, stream>>>(feat1, ftt + FT1_OFF, 128, 4096);
  transpose_feat<<<dim3(16, 8, B_), 256, 0, stream>>>(feat2, ftt + FT2_OFF, 256, 1024);
  transpose_feat<<<dim3(4, 16, B_), 256, 0, stream>>>(feat3, ftt + FT3_OFF, 512, 256);
  transpose_feat<<<dim3(4, 8, B_), 256, 0, stream>>>(feat4, ftt + FT4_OFF, 256, 256);

  // 2) weight prep
  prep_all<<<1273, 256, 0, stream>>>(f1W, f2W, awW, soW, awb, sob,
                                     e0W, e1W, e2W, e3W, e4W,
                                     W1T, W2T, Wc, eWT, bcat);

  // 3) token 0 passthrough
  copy_x0<<<(B_ * P_ * C_) / 256, 256, 0, stream>>>(x, out);

  // 4) LN1 -> h1 bf16
  ln1_h<<<TOK, 256, 0, stream>>>(x, n1g, n1b, h1);

  // 5) scores GEMM: S = h1 @ Wc + bcat   (M=20480, N=96, K=256)
  gemm_bf16<2><<<dim3(320, 2), 256, 0, stream>>>(h1, Wc, bcat, S, nullptr, 96, 256);

  // 6) softmax / tanh+ref
  postproc<<<TOK, 128, 0, stream>>>(S, ref, wts, poss);

  // 7) fused gather + projection + residual -> out[:,1:]
  samp_gemm<<<dim3(512, 5), 256, 0, stream>>>(x, ftt, wts, poss, eWT,
                                              e0b, e1b, e2b, e3b, e4b, out);

  // 8) LN2 -> h2 (reuses h1 buffer)
  ln2_h<<<TOK, 256, 0, stream>>>(out, n2g, n2b, h1);

  // 9) MLP GEMM1: u = gelu(h2 @ W1 + b1)   (M=20480, N=512, K=256)
  gemm_bf16<0><<<dim3(320, 8), 256, 0, stream>>>(h1, W1T, f1b, u, nullptr, 512, 256);

  // 10) MLP GEMM2: out += u @ W2 + b2      (M=20480, N=256, K=512)
  gemm_bf16<1><<<dim3(320, 4), 256, 0, stream>>>(u, W2T, f2b, nullptr, out, 256, 512);
}